// Round 1
// baseline (3009.881 us; speedup 1.0000x reference)
//
#include <hip/hip_runtime.h>

// GRU_10746008175428: 2-layer GRU + head, MI355X fp32 baseline.
// B=512 T=512 E=64 H=128 P=96.
//
// Design: per-layer persistent recurrence kernel. Each block owns NB=2 batch
// rows, loops T steps with h in LDS. W_ih and W_hh rows live in VGPRs,
// split across lane pairs (thread = (g, half)); x@W_ih^T is computed
// on-the-fly (no xg materialization -> saves ~1.6 GB HBM traffic, ws needs
// only h1 = 128 MB). fp32 everywhere for a correctness-first baseline.

#define B_SZ 512
#define T_SZ 512
#define E_SZ 64
#define H_SZ 128
#define G3   384
#define P_SZ 96

__device__ __forceinline__ float sigm(float x) {
    return 1.0f / (1.0f + __expf(-x));
}

template<int K_IN, bool WRITE_ALL>
__global__ __launch_bounds__(768, 3)
void gru_layer(const float* __restrict__ xin,   // (B, T, K_IN)
               const float* __restrict__ W_ih,  // (384, K_IN)
               const float* __restrict__ W_hh,  // (384, 128)
               const float* __restrict__ b_ih,  // (384,)
               const float* __restrict__ b_hh,  // (384,)
               float* __restrict__ hout)        // WRITE_ALL ? (B,T,128) : (B,128)
{
    constexpr int NB = 2;
    constexpr int KH = K_IN / 2;   // x-weights per thread (half row)
    constexpr int F4 = K_IN / 4;   // float4 per input row

    __shared__ float h_lds[NB][H_SZ];
    __shared__ float x_lds[NB][K_IN];
    __shared__ float sgx[NB][G3];
    __shared__ float sgh[NB][G3];

    const int tid  = threadIdx.x;
    const int g    = tid >> 1;     // gate row 0..383
    const int half = tid & 1;      // k-half
    const int b0   = blockIdx.x * NB;

    // ---- load this thread's weight slices into registers (one-time) ----
    float wih[KH];
    float whh[64];
    {
        const float* ws = W_ih + g * K_IN + half * KH;
        #pragma unroll
        for (int i = 0; i < KH; i += 4) {
            float4 w = *reinterpret_cast<const float4*>(ws + i);
            wih[i] = w.x; wih[i+1] = w.y; wih[i+2] = w.z; wih[i+3] = w.w;
        }
    }
    {
        const float* ws = W_hh + g * H_SZ + half * 64;
        #pragma unroll
        for (int i = 0; i < 64; i += 4) {
            float4 w = *reinterpret_cast<const float4*>(ws + i);
            whh[i] = w.x; whh[i+1] = w.y; whh[i+2] = w.z; whh[i+3] = w.w;
        }
    }
    const float bi = b_ih[g];
    const float bh = b_hh[g];

    // ---- init hidden state ----
    if (tid < NB * H_SZ) {
        h_lds[tid >> 7][tid & 127] = 0.0f;
    }

    const float4* xin4 = reinterpret_cast<const float4*>(xin);

    for (int t = 0; t < T_SZ; ++t) {
        // stage x_t for NB rows (coalesced float4)
        if (tid < NB * F4) {
            const int b  = tid / F4;
            const int k4 = tid % F4;
            float4 v = xin4[((size_t)(b0 + b) * T_SZ + t) * F4 + k4];
            *reinterpret_cast<float4*>(&x_lds[b][k4 * 4]) = v;
        }
        __syncthreads();

        // partial dot products: sx = x.Wih_half, sh = h.Whh_half
        #pragma unroll
        for (int b = 0; b < NB; ++b) {
            const float* xp = &x_lds[b][half * KH];
            const float* hp = &h_lds[b][half * 64];
            float ax0 = 0.f, ax1 = 0.f, ax2 = 0.f, ax3 = 0.f;
            float ah0 = 0.f, ah1 = 0.f, ah2 = 0.f, ah3 = 0.f;
            #pragma unroll
            for (int i = 0; i < KH; i += 4) {
                float4 xv = *reinterpret_cast<const float4*>(xp + i);
                ax0 += wih[i]   * xv.x;
                ax1 += wih[i+1] * xv.y;
                ax2 += wih[i+2] * xv.z;
                ax3 += wih[i+3] * xv.w;
            }
            #pragma unroll
            for (int i = 0; i < 64; i += 4) {
                float4 hv = *reinterpret_cast<const float4*>(hp + i);
                ah0 += whh[i]   * hv.x;
                ah1 += whh[i+1] * hv.y;
                ah2 += whh[i+2] * hv.z;
                ah3 += whh[i+3] * hv.w;
            }
            float sx = (ax0 + ax1) + (ax2 + ax3);
            float sh = (ah0 + ah1) + (ah2 + ah3);
            sx += __shfl_xor(sx, 1, 64);   // combine k-halves (lane pair)
            sh += __shfl_xor(sh, 1, 64);
            if (half == 0) {
                sgx[b][g] = sx + bi;
                sgh[b][g] = sh + bh;
            }
        }
        __syncthreads();

        // gate nonlinearities + state update (256 threads)
        if (tid < NB * H_SZ) {
            const int b = tid >> 7;
            const int u = tid & 127;
            float rx = sgx[b][u],       rh = sgh[b][u];
            float zx = sgx[b][u + 128], zh = sgh[b][u + 128];
            float nx = sgx[b][u + 256], nh = sgh[b][u + 256];
            float r = sigm(rx + rh);
            float z = sigm(zx + zh);
            float nv = nx + r * nh;
            nv = fminf(fmaxf(nv, -30.0f), 30.0f);   // avoid inf/inf NaN
            float e  = __expf(-2.0f * nv);
            float n  = (1.0f - e) / (1.0f + e);     // tanh(nv)
            float hold = h_lds[b][u];
            float hnew = (1.0f - z) * n + z * hold;
            h_lds[b][u] = hnew;
            if (WRITE_ALL) {
                hout[((size_t)(b0 + b) * T_SZ + t) * H_SZ + u] = hnew;
            } else if (t == T_SZ - 1) {
                hout[(size_t)(b0 + b) * H_SZ + u] = hnew;
            }
        }
        __syncthreads();
    }
}

__global__ __launch_bounds__(256)
void head_kernel(const float* __restrict__ h2,   // (B, H)
                 const float* __restrict__ W,    // (P, H)
                 const float* __restrict__ bias, // (P,)
                 float* __restrict__ out)        // (B, P)
{
    int idx = blockIdx.x * 256 + threadIdx.x;
    if (idx >= B_SZ * P_SZ) return;
    int b = idx / P_SZ;
    int p = idx % P_SZ;
    const float* hv = h2 + b * H_SZ;
    const float* wv = W  + p * H_SZ;
    float a0 = 0.f, a1 = 0.f, a2 = 0.f, a3 = 0.f;
    #pragma unroll
    for (int i = 0; i < H_SZ; i += 4) {
        float4 h4 = *reinterpret_cast<const float4*>(hv + i);
        float4 w4 = *reinterpret_cast<const float4*>(wv + i);
        a0 += h4.x * w4.x;
        a1 += h4.y * w4.y;
        a2 += h4.z * w4.z;
        a3 += h4.w * w4.w;
    }
    out[idx] = (a0 + a1) + (a2 + a3) + bias[p];
}

extern "C" void kernel_launch(void* const* d_in, const int* in_sizes, int n_in,
                              void* d_out, int out_size, void* d_ws, size_t ws_size,
                              hipStream_t stream)
{
    const float* x      = (const float*)d_in[0];
    const float* W_ih0  = (const float*)d_in[1];
    const float* W_hh0  = (const float*)d_in[2];
    const float* b_ih0  = (const float*)d_in[3];
    const float* b_hh0  = (const float*)d_in[4];
    const float* W_ih1  = (const float*)d_in[5];
    const float* W_hh1  = (const float*)d_in[6];
    const float* b_ih1  = (const float*)d_in[7];
    const float* b_hh1  = (const float*)d_in[8];
    const float* W_head = (const float*)d_in[9];
    const float* b_head = (const float*)d_in[10];
    float* out = (float*)d_out;

    float* h1 = (float*)d_ws;                       // (B,T,H) = 128 MB
    float* h2 = h1 + (size_t)B_SZ * T_SZ * H_SZ;    // (B,H)

    gru_layer<E_SZ, true ><<<B_SZ / 2, 768, 0, stream>>>(x,  W_ih0, W_hh0, b_ih0, b_hh0, h1);
    gru_layer<H_SZ, false><<<B_SZ / 2, 768, 0, stream>>>(h1, W_ih1, W_hh1, b_ih1, b_hh1, h2);
    head_kernel<<<(B_SZ * P_SZ + 255) / 256, 256, 0, stream>>>(h2, W_head, b_head, out);
}

// Round 2
// 1602.417 us; speedup vs baseline: 1.8783x; 1.8783x over previous
//
#include <hip/hip_runtime.h>

// GRU_10746008175428 round 2: MFMA recurrence.
// B=512 T=512 E=64 H=128 P=96. 2 layers + head.
// Per layer: 32 blocks x 512 threads (8 waves), NB=16 batch rows/block.
// Step = (16 x K_IN)@(K_IN x 384) [xg, fused] + (16 x 128)@(128 x 384) [hh]
// via v_mfma_f32_16x16x32_f16. Weights resident in VGPRs as B-frags.
// W_hh split hi/lo fp16 (lo scaled x2048 vs fp16 subnormals) -> ~fp32 weights.
// h: fp32 in regs (thread owns its D-fragment); fp16 copy via 4KB swizzled
// double-buffered LDS for next step's A-frags. One barrier per step.

#define B_SZ 512
#define T_SZ 512
#define E_SZ 64
#define H_SZ 128
#define P_SZ 96
#define NB   16
#define LO_SCALE 2048.0f
#define LO_INV   (1.0f/2048.0f)

typedef _Float16 half8 __attribute__((ext_vector_type(8)));
typedef float    f32x4 __attribute__((ext_vector_type(4)));

__device__ __forceinline__ float sigm(float x) { return 1.f / (1.f + __expf(-x)); }
__device__ __forceinline__ float tanhf_(float x) {
    x = fminf(fmaxf(x, -20.f), 20.f);
    float e = __expf(-2.f * x);
    return (1.f - e) / (1.f + e);
}
// XOR-swizzled byte offset in a [rows][256B] LDS tile (G4 recipe)
__device__ __forceinline__ int swz256(int row, int byte) {
    return row * 256 + (byte ^ ((row & 7) << 4));
}

// One B-fragment (16 cols x 32 k) from fp32 weight matrix W (row n = output
// col, ld = ldk). lane: col n0+(ln&15), k = kt*32 + (ln>>4)*8 + j.
__device__ __forceinline__ void load_bfrag(const float* __restrict__ W, int ldk,
                                           int n0, int kt, int ln,
                                           half8* hi, half8* lo) {
    int n = n0 + (ln & 15);
    int k = kt * 32 + (ln >> 4) * 8;
    const float* p = W + (size_t)n * ldk + k;
    float4 a = *(const float4*)p;
    float4 b = *(const float4*)(p + 4);
    float v[8] = {a.x, a.y, a.z, a.w, b.x, b.y, b.z, b.w};
    half8 h, l;
    #pragma unroll
    for (int j = 0; j < 8; ++j) {
        _Float16 hh = (_Float16)v[j];
        h[j] = hh;
        l[j] = (_Float16)((v[j] - (float)hh) * LO_SCALE);
    }
    *hi = h;
    if (lo) *lo = l;
}

#define LOADX(Sx, Sf, tt)                                                          \
    if ((tt) < T_SZ) {                                                             \
        if constexpr (XF16) {                                                      \
            _Pragma("unroll") for (int kt = 0; kt < KFX; ++kt)                     \
                Sx[kt] = *(const half8*)(xlane + (size_t)(tt) * 256 + kt * 64);    \
        } else {                                                                   \
            _Pragma("unroll") for (int kt = 0; kt < KFX; ++kt) {                   \
                Sf[kt][0] = *(const float4*)(xlane + (size_t)(tt) * 256 + kt * 128);      \
                Sf[kt][1] = *(const float4*)(xlane + (size_t)(tt) * 256 + kt * 128 + 16); \
            }                                                                      \
        }                                                                          \
    }

#define GRU_STEP(Sx, Sf, tcur, tnext)                                              \
    {                                                                              \
        const char* hb = hs[(tcur) & 1];                                           \
        half8 ah[4];                                                               \
        _Pragma("unroll") for (int kt = 0; kt < 4; ++kt)                           \
            ah[kt] = *(const half8*)(hb + swz256(colg, kt * 64 + rgrp * 16));      \
        f32x4 ax0 = {bi0, bi0, bi0, bi0};                                          \
        f32x4 ax1 = {bi1, bi1, bi1, bi1};                                          \
        f32x4 ax2 = {bi2, bi2, bi2, bi2};                                          \
        f32x4 ah0 = {bh0, bh0, bh0, bh0};                                          \
        f32x4 ah1 = {bh1, bh1, bh1, bh1};                                          \
        f32x4 ah2 = {bh2, bh2, bh2, bh2};                                          \
        f32x4 al0 = {0.f, 0.f, 0.f, 0.f};                                          \
        f32x4 al1 = al0, al2 = al0;                                                \
        half8 axf[KFX];                                                            \
        if constexpr (XF16) {                                                      \
            _Pragma("unroll") for (int kt = 0; kt < KFX; ++kt) axf[kt] = Sx[kt];   \
        } else {                                                                   \
            _Pragma("unroll") for (int kt = 0; kt < KFX; ++kt) {                   \
                half8 a;                                                           \
                a[0] = (_Float16)Sf[kt][0].x; a[1] = (_Float16)Sf[kt][0].y;        \
                a[2] = (_Float16)Sf[kt][0].z; a[3] = (_Float16)Sf[kt][0].w;        \
                a[4] = (_Float16)Sf[kt][1].x; a[5] = (_Float16)Sf[kt][1].y;        \
                a[6] = (_Float16)Sf[kt][1].z; a[7] = (_Float16)Sf[kt][1].w;        \
                axf[kt] = a;                                                       \
            }                                                                      \
        }                                                                          \
        _Pragma("unroll") for (int kt = 0; kt < KFX; ++kt) {                       \
            ax0 = __builtin_amdgcn_mfma_f32_16x16x32_f16(axf[kt], bx[0][kt], ax0, 0, 0, 0); \
            ax1 = __builtin_amdgcn_mfma_f32_16x16x32_f16(axf[kt], bx[1][kt], ax1, 0, 0, 0); \
            ax2 = __builtin_amdgcn_mfma_f32_16x16x32_f16(axf[kt], bx[2][kt], ax2, 0, 0, 0); \
        }                                                                          \
        _Pragma("unroll") for (int kt = 0; kt < 4; ++kt) {                         \
            ah0 = __builtin_amdgcn_mfma_f32_16x16x32_f16(ah[kt], bhh[0][kt], ah0, 0, 0, 0); \
            ah1 = __builtin_amdgcn_mfma_f32_16x16x32_f16(ah[kt], bhh[1][kt], ah1, 0, 0, 0); \
            ah2 = __builtin_amdgcn_mfma_f32_16x16x32_f16(ah[kt], bhh[2][kt], ah2, 0, 0, 0); \
            al0 = __builtin_amdgcn_mfma_f32_16x16x32_f16(ah[kt], bhl[0][kt], al0, 0, 0, 0); \
            al1 = __builtin_amdgcn_mfma_f32_16x16x32_f16(ah[kt], bhl[1][kt], al1, 0, 0, 0); \
            al2 = __builtin_amdgcn_mfma_f32_16x16x32_f16(ah[kt], bhl[2][kt], al2, 0, 0, 0); \
        }                                                                          \
        LOADX(Sx, Sf, tnext)                                                       \
        float hn[4];                                                               \
        _Pragma("unroll") for (int j = 0; j < 4; ++j) {                            \
            float rr  = sigm(ax0[j] + ah0[j] + al0[j] * LO_INV);                   \
            float zz  = sigm(ax1[j] + ah1[j] + al1[j] * LO_INV);                   \
            float hnv = ah2[j] + al2[j] * LO_INV;                                  \
            float nn  = tanhf_(ax2[j] + rr * hnv);                                 \
            hn[j] = (1.f - zz) * nn + zz * hreg[j];                                \
            hreg[j] = hn[j];                                                       \
        }                                                                          \
        char* hw = hs[((tcur) + 1) & 1];                                           \
        _Pragma("unroll") for (int j = 0; j < 4; ++j) {                            \
            int bb = rgrp * 4 + j;                                                 \
            *(_Float16*)(hw + swz256(bb, cw * 2)) = (_Float16)hn[j];               \
            if constexpr (OUT_ALL) {                                               \
                ((_Float16*)hout)[((size_t)(b0 + bb) * T_SZ + (tcur)) * H_SZ + cw] \
                    = (_Float16)hn[j];                                             \
            } else {                                                               \
                if ((tcur) == T_SZ - 1)                                            \
                    ((float*)hout)[(size_t)(b0 + bb) * H_SZ + cw] = hn[j];         \
            }                                                                      \
        }                                                                          \
        __syncthreads();                                                           \
    }

template<int K_IN, bool XF16, bool OUT_ALL>
__global__ __launch_bounds__(512)
void gru_mfma(const void* __restrict__ xin,    // (B,T,K_IN) fp32 or fp16: 256B rows
              const float* __restrict__ W_ih,  // (384, K_IN)
              const float* __restrict__ W_hh,  // (384, 128)
              const float* __restrict__ b_ih,
              const float* __restrict__ b_hh,
              void* __restrict__ hout)         // OUT_ALL ? (B,T,128) fp16 : (B,128) f32
{
    constexpr int KFX = K_IN / 32;
    __shared__ __align__(16) char hs[2][4096];   // double-buffered h (fp16, swizzled)

    const int tid  = threadIdx.x;
    const int ln   = tid & 63;
    const int wv   = tid >> 6;        // wave 0..7 -> col tile
    const int colg = ln & 15;
    const int rgrp = ln >> 4;
    const int b0   = blockIdx.x * NB;
    const int cw   = wv * 16 + colg;  // hidden-unit column 0..127

    // ---- resident weight fragments ----
    half8 bx[3][KFX];        // W_ih (single fp16)
    half8 bhh[3][4];         // W_hh hi
    half8 bhl[3][4];         // W_hh lo (x2048)
    #pragma unroll
    for (int g = 0; g < 3; ++g) {
        int n0 = g * 128 + wv * 16;
        #pragma unroll
        for (int kt = 0; kt < KFX; ++kt)
            load_bfrag(W_ih, K_IN, n0, kt, ln, &bx[g][kt], nullptr);
        #pragma unroll
        for (int kt = 0; kt < 4; ++kt)
            load_bfrag(W_hh, H_SZ, n0, kt, ln, &bhh[g][kt], &bhl[g][kt]);
    }
    const float bi0 = b_ih[cw], bi1 = b_ih[128 + cw], bi2 = b_ih[256 + cw];
    const float bh0 = b_hh[cw], bh1 = b_hh[128 + cw], bh2 = b_hh[256 + cw];

    if (tid < 256) *(float4*)(hs[0] + tid * 16) = make_float4(0.f, 0.f, 0.f, 0.f);
    float hreg[4] = {0.f, 0.f, 0.f, 0.f};

    // per-lane x row base: A-row = colg (batch), k-offset rgrp*8
    const char* xlane = (const char*)xin
        + (size_t)(b0 + colg) * T_SZ * 256
        + rgrp * (XF16 ? 16 : 32);

    half8  Ax[KFX], Bx2[KFX];
    float4 Af[KFX][2], Bf[KFX][2];

    LOADX(Ax, Af, 0)
    LOADX(Bx2, Bf, 1)
    __syncthreads();

    for (int t = 0; t < T_SZ; t += 2) {
        GRU_STEP(Ax,  Af, t,     t + 2)
        GRU_STEP(Bx2, Bf, t + 1, t + 3)
    }
}

__global__ __launch_bounds__(256)
void head_kernel(const float* __restrict__ h2,   // (B, H)
                 const float* __restrict__ W,    // (P, H)
                 const float* __restrict__ bias, // (P,)
                 float* __restrict__ out)        // (B, P)
{
    int idx = blockIdx.x * 256 + threadIdx.x;
    if (idx >= B_SZ * P_SZ) return;
    int b = idx / P_SZ;
    int p = idx % P_SZ;
    const float* hv = h2 + b * H_SZ;
    const float* wv = W + p * H_SZ;
    float a0 = 0.f, a1 = 0.f, a2 = 0.f, a3 = 0.f;
    #pragma unroll
    for (int i = 0; i < H_SZ; i += 4) {
        float4 h4 = *(const float4*)(hv + i);
        float4 w4 = *(const float4*)(wv + i);
        a0 += h4.x * w4.x;
        a1 += h4.y * w4.y;
        a2 += h4.z * w4.z;
        a3 += h4.w * w4.w;
    }
    out[idx] = (a0 + a1) + (a2 + a3) + bias[p];
}

extern "C" void kernel_launch(void* const* d_in, const int* in_sizes, int n_in,
                              void* d_out, int out_size, void* d_ws, size_t ws_size,
                              hipStream_t stream)
{
    const float* x      = (const float*)d_in[0];
    const float* W_ih0  = (const float*)d_in[1];
    const float* W_hh0  = (const float*)d_in[2];
    const float* b_ih0  = (const float*)d_in[3];
    const float* b_hh0  = (const float*)d_in[4];
    const float* W_ih1  = (const float*)d_in[5];
    const float* W_hh1  = (const float*)d_in[6];
    const float* b_ih1  = (const float*)d_in[7];
    const float* b_hh1  = (const float*)d_in[8];
    const float* W_head = (const float*)d_in[9];
    const float* b_head = (const float*)d_in[10];
    float* out = (float*)d_out;

    _Float16* h1 = (_Float16*)d_ws;                               // (B,T,128) fp16 = 64 MB
    float*    h2 = (float*)((char*)d_ws + (size_t)B_SZ * T_SZ * H_SZ * 2);  // (B,128) f32

    gru_mfma<E_SZ, false, true ><<<B_SZ / NB, 512, 0, stream>>>(x,  W_ih0, W_hh0, b_ih0, b_hh0, h1);
    gru_mfma<H_SZ, true,  false><<<B_SZ / NB, 512, 0, stream>>>(h1, W_ih1, W_hh1, b_ih1, b_hh1, h2);
    head_kernel<<<(B_SZ * P_SZ + 255) / 256, 256, 0, stream>>>(h2, W_head, b_head, out);
}

// Round 3
// 1444.708 us; speedup vs baseline: 2.0834x; 1.1092x over previous
//
#include <hip/hip_runtime.h>

// GRU_10746008175428 round 3: MFMA recurrence + non-draining barrier.
// B=512 T=512 E=64 H=128 P=96. 2 layers + head.
// Per layer: 32 blocks x 512 threads (8 waves), NB=16 batch rows/block.
// Step = (16 x K_IN)@(K_IN x 384) [xg, fused] + (16 x 128)@(128 x 384) [hh]
// via v_mfma_f32_16x16x32_f16. Weights resident in VGPRs as B-frags.
// W_hh split hi/lo fp16 (lo scaled x2048) -> ~fp32 weights.
// Round-3 change: per-step barrier is lgkmcnt-only s_barrier (NOT
// __syncthreads) so the x-prefetch globals + h1 stores stay in flight
// across steps; biases folded into gate phase (acc init = inline 0).

#define B_SZ 512
#define T_SZ 512
#define E_SZ 64
#define H_SZ 128
#define P_SZ 96
#define NB   16
#define LO_SCALE 2048.0f
#define LO_INV   (1.0f/2048.0f)

typedef _Float16 half8 __attribute__((ext_vector_type(8)));
typedef float    f32x4 __attribute__((ext_vector_type(4)));

__device__ __forceinline__ float sigm(float x) { return 1.f / (1.f + __expf(-x)); }
__device__ __forceinline__ float tanhf_(float x) {
    x = fminf(fmaxf(x, -20.f), 20.f);
    float e = __expf(-2.f * x);
    return (1.f - e) / (1.f + e);
}
// XOR-swizzled byte offset in a [rows][256B] LDS tile (G4 recipe)
__device__ __forceinline__ int swz256(int row, int byte) {
    return row * 256 + (byte ^ ((row & 7) << 4));
}

// One B-fragment (16 cols x 32 k) from fp32 weight matrix W (row n = output
// col, ld = ldk). lane: col n0+(ln&15), k = kt*32 + (ln>>4)*8 + j.
__device__ __forceinline__ void load_bfrag(const float* __restrict__ W, int ldk,
                                           int n0, int kt, int ln,
                                           half8* hi, half8* lo) {
    int n = n0 + (ln & 15);
    int k = kt * 32 + (ln >> 4) * 8;
    const float* p = W + (size_t)n * ldk + k;
    float4 a = *(const float4*)p;
    float4 b = *(const float4*)(p + 4);
    float v[8] = {a.x, a.y, a.z, a.w, b.x, b.y, b.z, b.w};
    half8 h, l;
    #pragma unroll
    for (int j = 0; j < 8; ++j) {
        _Float16 hh = (_Float16)v[j];
        h[j] = hh;
        l[j] = (_Float16)((v[j] - (float)hh) * LO_SCALE);
    }
    *hi = h;
    if (lo) *lo = l;
}

#define LOADX(Sx, Sf, tt)                                                          \
    if ((tt) < T_SZ) {                                                             \
        if constexpr (XF16) {                                                      \
            _Pragma("unroll") for (int kt = 0; kt < KFX; ++kt)                     \
                Sx[kt] = *(const half8*)(xlane + (size_t)(tt) * 256 + kt * 64);    \
        } else {                                                                   \
            _Pragma("unroll") for (int kt = 0; kt < KFX; ++kt) {                   \
                Sf[kt][0] = *(const float4*)(xlane + (size_t)(tt) * 256 + kt * 128);      \
                Sf[kt][1] = *(const float4*)(xlane + (size_t)(tt) * 256 + kt * 128 + 16); \
            }                                                                      \
        }                                                                          \
    }

#define GRU_STEP(Sx, Sf, tcur, tnext)                                              \
    {                                                                              \
        const char* hb = hs[(tcur) & 1];                                           \
        half8 ah[4];                                                               \
        _Pragma("unroll") for (int kt = 0; kt < 4; ++kt)                           \
            ah[kt] = *(const half8*)(hb + swz256(colg, kt * 64 + rgrp * 16));      \
        f32x4 ax0 = {0.f, 0.f, 0.f, 0.f};                                          \
        f32x4 ax1 = ax0, ax2 = ax0;                                                \
        f32x4 ah0 = ax0, ah1 = ax0, ah2 = ax0;                                     \
        f32x4 al0 = ax0, al1 = ax0, al2 = ax0;                                     \
        half8 axf[KFX];                                                            \
        if constexpr (XF16) {                                                      \
            _Pragma("unroll") for (int kt = 0; kt < KFX; ++kt) axf[kt] = Sx[kt];   \
        } else {                                                                   \
            _Pragma("unroll") for (int kt = 0; kt < KFX; ++kt) {                   \
                half8 a;                                                           \
                a[0] = (_Float16)Sf[kt][0].x; a[1] = (_Float16)Sf[kt][0].y;        \
                a[2] = (_Float16)Sf[kt][0].z; a[3] = (_Float16)Sf[kt][0].w;        \
                a[4] = (_Float16)Sf[kt][1].x; a[5] = (_Float16)Sf[kt][1].y;        \
                a[6] = (_Float16)Sf[kt][1].z; a[7] = (_Float16)Sf[kt][1].w;        \
                axf[kt] = a;                                                       \
            }                                                                      \
        }                                                                          \
        _Pragma("unroll") for (int kt = 0; kt < KFX; ++kt) {                       \
            ax0 = __builtin_amdgcn_mfma_f32_16x16x32_f16(axf[kt], bx[0][kt], ax0, 0, 0, 0); \
            ax1 = __builtin_amdgcn_mfma_f32_16x16x32_f16(axf[kt], bx[1][kt], ax1, 0, 0, 0); \
            ax2 = __builtin_amdgcn_mfma_f32_16x16x32_f16(axf[kt], bx[2][kt], ax2, 0, 0, 0); \
        }                                                                          \
        _Pragma("unroll") for (int kt = 0; kt < 4; ++kt) {                         \
            ah0 = __builtin_amdgcn_mfma_f32_16x16x32_f16(ah[kt], bhh[0][kt], ah0, 0, 0, 0); \
            ah1 = __builtin_amdgcn_mfma_f32_16x16x32_f16(ah[kt], bhh[1][kt], ah1, 0, 0, 0); \
            ah2 = __builtin_amdgcn_mfma_f32_16x16x32_f16(ah[kt], bhh[2][kt], ah2, 0, 0, 0); \
            al0 = __builtin_amdgcn_mfma_f32_16x16x32_f16(ah[kt], bhl[0][kt], al0, 0, 0, 0); \
            al1 = __builtin_amdgcn_mfma_f32_16x16x32_f16(ah[kt], bhl[1][kt], al1, 0, 0, 0); \
            al2 = __builtin_amdgcn_mfma_f32_16x16x32_f16(ah[kt], bhl[2][kt], al2, 0, 0, 0); \
        }                                                                          \
        LOADX(Sx, Sf, tnext)                                                       \
        float hn[4];                                                               \
        _Pragma("unroll") for (int j = 0; j < 4; ++j) {                            \
            float rr  = sigm(ax0[j] + ah0[j] + al0[j] * LO_INV + bs0);             \
            float zz  = sigm(ax1[j] + ah1[j] + al1[j] * LO_INV + bs1);             \
            float hnv = ah2[j] + al2[j] * LO_INV + bh2;                            \
            float nn  = tanhf_(ax2[j] + bi2 + rr * hnv);                           \
            hn[j] = (1.f - zz) * nn + zz * hreg[j];                                \
            hreg[j] = hn[j];                                                       \
        }                                                                          \
        char* hw = hs[((tcur) + 1) & 1];                                           \
        _Pragma("unroll") for (int j = 0; j < 4; ++j) {                            \
            int bb = rgrp * 4 + j;                                                 \
            *(_Float16*)(hw + swz256(bb, cw * 2)) = (_Float16)hn[j];               \
            if constexpr (OUT_ALL) {                                               \
                ((_Float16*)hout)[((size_t)(b0 + bb) * T_SZ + (tcur)) * H_SZ + cw] \
                    = (_Float16)hn[j];                                             \
            } else {                                                               \
                if ((tcur) == T_SZ - 1)                                            \
                    ((float*)hout)[(size_t)(b0 + bb) * H_SZ + cw] = hn[j];         \
            }                                                                      \
        }                                                                          \
        /* lgkm-only barrier: keep global loads/stores in flight across steps */   \
        asm volatile("s_waitcnt lgkmcnt(0)" ::: "memory");                         \
        __builtin_amdgcn_s_barrier();                                              \
        __builtin_amdgcn_sched_barrier(0);                                         \
    }

template<int K_IN, bool XF16, bool OUT_ALL>
__global__ __launch_bounds__(512)
void gru_mfma(const void* __restrict__ xin,    // (B,T,K_IN) fp32 or fp16: 256B rows
              const float* __restrict__ W_ih,  // (384, K_IN)
              const float* __restrict__ W_hh,  // (384, 128)
              const float* __restrict__ b_ih,
              const float* __restrict__ b_hh,
              void* __restrict__ hout)         // OUT_ALL ? (B,T,128) fp16 : (B,128) f32
{
    constexpr int KFX = K_IN / 32;
    __shared__ __align__(16) char hs[2][4096];   // double-buffered h (fp16, swizzled)

    const int tid  = threadIdx.x;
    const int ln   = tid & 63;
    const int wv   = tid >> 6;        // wave 0..7 -> col tile
    const int colg = ln & 15;
    const int rgrp = ln >> 4;
    const int b0   = blockIdx.x * NB;
    const int cw   = wv * 16 + colg;  // hidden-unit column 0..127

    // ---- resident weight fragments ----
    half8 bx[3][KFX];        // W_ih (single fp16)
    half8 bhh[3][4];         // W_hh hi
    half8 bhl[3][4];         // W_hh lo (x2048)
    #pragma unroll
    for (int g = 0; g < 3; ++g) {
        int n0 = g * 128 + wv * 16;
        #pragma unroll
        for (int kt = 0; kt < KFX; ++kt)
            load_bfrag(W_ih, K_IN, n0, kt, ln, &bx[g][kt], nullptr);
        #pragma unroll
        for (int kt = 0; kt < 4; ++kt)
            load_bfrag(W_hh, H_SZ, n0, kt, ln, &bhh[g][kt], &bhl[g][kt]);
    }
    const float bs0 = b_ih[cw] + b_hh[cw];
    const float bs1 = b_ih[128 + cw] + b_hh[128 + cw];
    const float bi2 = b_ih[256 + cw];
    const float bh2 = b_hh[256 + cw];

    if (tid < 256) *(float4*)(hs[0] + tid * 16) = make_float4(0.f, 0.f, 0.f, 0.f);
    float hreg[4] = {0.f, 0.f, 0.f, 0.f};

    // per-lane x row base: A-row = colg (batch), k-offset rgrp*8
    const char* xlane = (const char*)xin
        + (size_t)(b0 + colg) * T_SZ * 256
        + rgrp * (XF16 ? 16 : 32);

    half8  Ax[KFX], Bx2[KFX];
    float4 Af[KFX][2], Bf[KFX][2];

    LOADX(Ax, Af, 0)
    LOADX(Bx2, Bf, 1)
    __syncthreads();

    for (int t = 0; t < T_SZ; t += 2) {
        GRU_STEP(Ax,  Af, t,     t + 2)
        GRU_STEP(Bx2, Bf, t + 1, t + 3)
    }
}

__global__ __launch_bounds__(256)
void head_kernel(const float* __restrict__ h2,   // (B, H)
                 const float* __restrict__ W,    // (P, H)
                 const float* __restrict__ bias, // (P,)
                 float* __restrict__ out)        // (B, P)
{
    int idx = blockIdx.x * 256 + threadIdx.x;
    if (idx >= B_SZ * P_SZ) return;
    int b = idx / P_SZ;
    int p = idx % P_SZ;
    const float* hv = h2 + b * H_SZ;
    const float* wv = W + p * H_SZ;
    float a0 = 0.f, a1 = 0.f, a2 = 0.f, a3 = 0.f;
    #pragma unroll
    for (int i = 0; i < H_SZ; i += 4) {
        float4 h4 = *(const float4*)(hv + i);
        float4 w4 = *(const float4*)(wv + i);
        a0 += h4.x * w4.x;
        a1 += h4.y * w4.y;
        a2 += h4.z * w4.z;
        a3 += h4.w * w4.w;
    }
    out[idx] = (a0 + a1) + (a2 + a3) + bias[p];
}

extern "C" void kernel_launch(void* const* d_in, const int* in_sizes, int n_in,
                              void* d_out, int out_size, void* d_ws, size_t ws_size,
                              hipStream_t stream)
{
    const float* x      = (const float*)d_in[0];
    const float* W_ih0  = (const float*)d_in[1];
    const float* W_hh0  = (const float*)d_in[2];
    const float* b_ih0  = (const float*)d_in[3];
    const float* b_hh0  = (const float*)d_in[4];
    const float* W_ih1  = (const float*)d_in[5];
    const float* W_hh1  = (const float*)d_in[6];
    const float* b_ih1  = (const float*)d_in[7];
    const float* b_hh1  = (const float*)d_in[8];
    const float* W_head = (const float*)d_in[9];
    const float* b_head = (const float*)d_in[10];
    float* out = (float*)d_out;

    _Float16* h1 = (_Float16*)d_ws;                               // (B,T,128) fp16 = 64 MB
    float*    h2 = (float*)((char*)d_ws + (size_t)B_SZ * T_SZ * H_SZ * 2);  // (B,128) f32

    gru_mfma<E_SZ, false, true ><<<B_SZ / NB, 512, 0, stream>>>(x,  W_ih0, W_hh0, b_ih0, b_hh0, h1);
    gru_mfma<H_SZ, true,  false><<<B_SZ / NB, 512, 0, stream>>>(h1, W_ih1, W_hh1, b_ih1, b_hh1, h2);
    head_kernel<<<(B_SZ * P_SZ + 255) / 256, 256, 0, stream>>>(h2, W_head, b_head, out);
}

// Round 4
// 960.424 us; speedup vs baseline: 3.1339x; 1.5042x over previous
//
#include <hip/hip_runtime.h>

// GRU_10746008175428 round 4: MFMA recurrence, slimmed instruction work.
// B=512 T=512 E=64 H=128 P=96. 2 layers + head.
// Per layer: 32 blocks x 512 threads (8 waves), NB=16 batch rows/block.
// vs round 3:
//  - W_hh lo-rail only on the n-gate (hh MFMA 24 -> 16 per wave/step);
//    r/z gates use fp16-hi weights only (error damped by sigmoid slope,
//    h is already fp16-quantized anyway).
//  - weights/biases pre-scaled by -log2e (r,z) / -2*log2e (n) so gates are
//    rcp(1+exp2(acc)) -- no scaling muls in the hot loop.
//  - biases folded into MFMA C-operand init (no bias adds in gate phase).
//  - lgkm-only barrier (round 3) retained.

#define B_SZ 512
#define T_SZ 512
#define E_SZ 64
#define H_SZ 128
#define P_SZ 96
#define NB   16
#define LO_SCALE 2048.0f
#define LO_INV   (1.0f/2048.0f)
#define SC_SIG  (-1.44269504f)   // -log2(e)
#define SC_TANH (-2.88539008f)   // -2*log2(e)

typedef _Float16 half8 __attribute__((ext_vector_type(8)));
typedef float    f32x4 __attribute__((ext_vector_type(4)));

__device__ __forceinline__ float exp2_(float x) {
#if __has_builtin(__builtin_amdgcn_exp2f)
    return __builtin_amdgcn_exp2f(x);
#else
    return exp2f(x);
#endif
}
__device__ __forceinline__ float rcp_(float x) {
#if __has_builtin(__builtin_amdgcn_rcpf)
    return __builtin_amdgcn_rcpf(x);
#else
    return 1.0f / x;
#endif
}

// XOR-swizzled byte offset in a [rows][256B] LDS tile (G4 recipe)
__device__ __forceinline__ int swz256(int row, int byte) {
    return row * 256 + (byte ^ ((row & 7) << 4));
}

// One B-fragment (16 cols x 32 k) from fp32 weight matrix W, pre-scaled.
// lane: col n0+(ln&15), k = kt*32 + (ln>>4)*8 + j.
__device__ __forceinline__ void load_bfrag(const float* __restrict__ W, int ldk,
                                           int n0, int kt, int ln, float scale,
                                           half8* hi, half8* lo) {
    int n = n0 + (ln & 15);
    int k = kt * 32 + (ln >> 4) * 8;
    const float* p = W + (size_t)n * ldk + k;
    float4 a = *(const float4*)p;
    float4 b = *(const float4*)(p + 4);
    float v[8] = {a.x, a.y, a.z, a.w, b.x, b.y, b.z, b.w};
    half8 h, l;
    #pragma unroll
    for (int j = 0; j < 8; ++j) {
        float w = v[j] * scale;
        _Float16 hh = (_Float16)w;
        h[j] = hh;
        l[j] = (_Float16)((w - (float)hh) * LO_SCALE);
    }
    *hi = h;
    if (lo) *lo = l;
}

#define LOADX(Sx, Sf, tt)                                                          \
    if ((tt) < T_SZ) {                                                             \
        if constexpr (XF16) {                                                      \
            _Pragma("unroll") for (int kt = 0; kt < KFX; ++kt)                     \
                Sx[kt] = *(const half8*)(xlane + (size_t)(tt) * 256 + kt * 64);    \
        } else {                                                                   \
            _Pragma("unroll") for (int kt = 0; kt < KFX; ++kt) {                   \
                Sf[kt][0] = *(const float4*)(xlane + (size_t)(tt) * 256 + kt * 128);      \
                Sf[kt][1] = *(const float4*)(xlane + (size_t)(tt) * 256 + kt * 128 + 16); \
            }                                                                      \
        }                                                                          \
    }

#define GRU_STEP(Sx, Sf, tcur, tnext)                                              \
    {                                                                              \
        const char* hb = hs[(tcur) & 1];                                           \
        half8 ah[4];                                                               \
        _Pragma("unroll") for (int kt = 0; kt < 4; ++kt)                           \
            ah[kt] = *(const half8*)(hb + swz256(colg, kt * 64 + rgrp * 16));      \
        f32x4 ax0 = {bs0, bs0, bs0, bs0};                                          \
        f32x4 ax1 = {bs1, bs1, bs1, bs1};                                          \
        f32x4 ax2 = {bi2s, bi2s, bi2s, bi2s};                                      \
        f32x4 ah2 = {bh2s, bh2s, bh2s, bh2s};                                      \
        f32x4 ah0 = {0.f, 0.f, 0.f, 0.f};                                          \
        f32x4 ah1 = ah0, al2 = ah0;                                                \
        half8 axf[KFX];                                                            \
        if constexpr (XF16) {                                                      \
            _Pragma("unroll") for (int kt = 0; kt < KFX; ++kt) axf[kt] = Sx[kt];   \
        } else {                                                                   \
            _Pragma("unroll") for (int kt = 0; kt < KFX; ++kt) {                   \
                half8 a;                                                           \
                a[0] = (_Float16)Sf[kt][0].x; a[1] = (_Float16)Sf[kt][0].y;        \
                a[2] = (_Float16)Sf[kt][0].z; a[3] = (_Float16)Sf[kt][0].w;        \
                a[4] = (_Float16)Sf[kt][1].x; a[5] = (_Float16)Sf[kt][1].y;        \
                a[6] = (_Float16)Sf[kt][1].z; a[7] = (_Float16)Sf[kt][1].w;        \
                axf[kt] = a;                                                       \
            }                                                                      \
        }                                                                          \
        _Pragma("unroll") for (int kt = 0; kt < KFX; ++kt) {                       \
            ax0 = __builtin_amdgcn_mfma_f32_16x16x32_f16(axf[kt], bx[0][kt], ax0, 0, 0, 0); \
            ax1 = __builtin_amdgcn_mfma_f32_16x16x32_f16(axf[kt], bx[1][kt], ax1, 0, 0, 0); \
            ax2 = __builtin_amdgcn_mfma_f32_16x16x32_f16(axf[kt], bx[2][kt], ax2, 0, 0, 0); \
        }                                                                          \
        _Pragma("unroll") for (int kt = 0; kt < 4; ++kt) {                         \
            ah0 = __builtin_amdgcn_mfma_f32_16x16x32_f16(ah[kt], bhh[0][kt], ah0, 0, 0, 0); \
            ah1 = __builtin_amdgcn_mfma_f32_16x16x32_f16(ah[kt], bhh[1][kt], ah1, 0, 0, 0); \
            ah2 = __builtin_amdgcn_mfma_f32_16x16x32_f16(ah[kt], bhh[2][kt], ah2, 0, 0, 0); \
            al2 = __builtin_amdgcn_mfma_f32_16x16x32_f16(ah[kt], bhl2[kt],   al2, 0, 0, 0); \
        }                                                                          \
        LOADX(Sx, Sf, tnext)                                                       \
        float hn_[4];                                                              \
        _Pragma("unroll") for (int j = 0; j < 4; ++j) {                            \
            float e0 = exp2_(ax0[j] + ah0[j]);                                     \
            float rr = rcp_(1.f + e0);                                             \
            float e1 = exp2_(ax1[j] + ah1[j]);                                     \
            float zz = rcp_(1.f + e1);                                             \
            float hnv = ah2[j] + al2[j] * LO_INV;                                  \
            float v  = ax2[j] + rr * hnv;                                          \
            v = fminf(fmaxf(v, -60.f), 60.f);                                      \
            float e2 = exp2_(v);                                                   \
            float nn = (1.f - e2) * rcp_(1.f + e2);                                \
            hn_[j] = nn + zz * (hreg[j] - nn);                                     \
            hreg[j] = hn_[j];                                                      \
        }                                                                          \
        char* hw = hs[((tcur) + 1) & 1];                                           \
        _Pragma("unroll") for (int j = 0; j < 4; ++j) {                            \
            int bb = rgrp * 4 + j;                                                 \
            *(_Float16*)(hw + swz256(bb, cw * 2)) = (_Float16)hn_[j];              \
            if constexpr (OUT_ALL) {                                               \
                ((_Float16*)hout)[((size_t)(b0 + bb) * T_SZ + (tcur)) * H_SZ + cw] \
                    = (_Float16)hn_[j];                                            \
            } else {                                                               \
                if ((tcur) == T_SZ - 1)                                            \
                    ((float*)hout)[(size_t)(b0 + bb) * H_SZ + cw] = hn_[j];        \
            }                                                                      \
        }                                                                          \
        /* lgkm-only barrier: keep global loads/stores in flight across steps */   \
        asm volatile("s_waitcnt lgkmcnt(0)" ::: "memory");                         \
        __builtin_amdgcn_s_barrier();                                              \
        __builtin_amdgcn_sched_barrier(0);                                         \
    }

template<int K_IN, bool XF16, bool OUT_ALL>
__global__ __launch_bounds__(512)
void gru_mfma(const void* __restrict__ xin,    // (B,T,K_IN) fp32 or fp16: 256B rows
              const float* __restrict__ W_ih,  // (384, K_IN)
              const float* __restrict__ W_hh,  // (384, 128)
              const float* __restrict__ b_ih,
              const float* __restrict__ b_hh,
              void* __restrict__ hout)         // OUT_ALL ? (B,T,128) fp16 : (B,128) f32
{
    constexpr int KFX = K_IN / 32;
    __shared__ __align__(16) char hs[2][4096];   // double-buffered h (fp16, swizzled)

    const int tid  = threadIdx.x;
    const int ln   = tid & 63;
    const int wv   = tid >> 6;        // wave 0..7 -> col tile
    const int colg = ln & 15;
    const int rgrp = ln >> 4;
    const int b0   = blockIdx.x * NB;
    const int cw   = wv * 16 + colg;  // hidden-unit column 0..127

    // ---- resident weight fragments (pre-scaled by gate) ----
    half8 bx[3][KFX];        // W_ih (fp16 hi only)
    half8 bhh[3][4];         // W_hh hi
    half8 bhl2[4];           // W_hh lo (x2048), n-gate only
    const float gsc[3] = {SC_SIG, SC_SIG, SC_TANH};
    #pragma unroll
    for (int g = 0; g < 3; ++g) {
        int n0 = g * 128 + wv * 16;
        #pragma unroll
        for (int kt = 0; kt < KFX; ++kt)
            load_bfrag(W_ih, K_IN, n0, kt, ln, gsc[g], &bx[g][kt], nullptr);
        #pragma unroll
        for (int kt = 0; kt < 4; ++kt)
            load_bfrag(W_hh, H_SZ, n0, kt, ln, gsc[g], &bhh[g][kt],
                       (g == 2) ? &bhl2[kt] : nullptr);
    }
    const float bs0  = SC_SIG  * (b_ih[cw] + b_hh[cw]);
    const float bs1  = SC_SIG  * (b_ih[128 + cw] + b_hh[128 + cw]);
    const float bi2s = SC_TANH * b_ih[256 + cw];
    const float bh2s = SC_TANH * b_hh[256 + cw];

    if (tid < 256) *(float4*)(hs[0] + tid * 16) = make_float4(0.f, 0.f, 0.f, 0.f);
    float hreg[4] = {0.f, 0.f, 0.f, 0.f};

    // per-lane x row base: A-row = colg (batch), k-offset rgrp*8
    const char* xlane = (const char*)xin
        + (size_t)(b0 + colg) * T_SZ * 256
        + rgrp * (XF16 ? 16 : 32);

    half8  Ax[KFX], Bx2[KFX];
    float4 Af[KFX][2], Bf[KFX][2];

    LOADX(Ax, Af, 0)
    LOADX(Bx2, Bf, 1)
    __syncthreads();

    for (int t = 0; t < T_SZ; t += 2) {
        GRU_STEP(Ax,  Af, t,     t + 2)
        GRU_STEP(Bx2, Bf, t + 1, t + 3)
    }
}

__global__ __launch_bounds__(256)
void head_kernel(const float* __restrict__ h2,   // (B, H)
                 const float* __restrict__ W,    // (P, H)
                 const float* __restrict__ bias, // (P,)
                 float* __restrict__ out)        // (B, P)
{
    int idx = blockIdx.x * 256 + threadIdx.x;
    if (idx >= B_SZ * P_SZ) return;
    int b = idx / P_SZ;
    int p = idx % P_SZ;
    const float* hv = h2 + b * H_SZ;
    const float* wv = W + p * H_SZ;
    float a0 = 0.f, a1 = 0.f, a2 = 0.f, a3 = 0.f;
    #pragma unroll
    for (int i = 0; i < H_SZ; i += 4) {
        float4 h4 = *(const float4*)(hv + i);
        float4 w4 = *(const float4*)(wv + i);
        a0 += h4.x * w4.x;
        a1 += h4.y * w4.y;
        a2 += h4.z * w4.z;
        a3 += h4.w * w4.w;
    }
    out[idx] = (a0 + a1) + (a2 + a3) + bias[p];
}

extern "C" void kernel_launch(void* const* d_in, const int* in_sizes, int n_in,
                              void* d_out, int out_size, void* d_ws, size_t ws_size,
                              hipStream_t stream)
{
    const float* x      = (const float*)d_in[0];
    const float* W_ih0  = (const float*)d_in[1];
    const float* W_hh0  = (const float*)d_in[2];
    const float* b_ih0  = (const float*)d_in[3];
    const float* b_hh0  = (const float*)d_in[4];
    const float* W_ih1  = (const float*)d_in[5];
    const float* W_hh1  = (const float*)d_in[6];
    const float* b_ih1  = (const float*)d_in[7];
    const float* b_hh1  = (const float*)d_in[8];
    const float* W_head = (const float*)d_in[9];
    const float* b_head = (const float*)d_in[10];
    float* out = (float*)d_out;

    _Float16* h1 = (_Float16*)d_ws;                               // (B,T,128) fp16 = 64 MB
    float*    h2 = (float*)((char*)d_ws + (size_t)B_SZ * T_SZ * H_SZ * 2);  // (B,128) f32

    gru_mfma<E_SZ, false, true ><<<B_SZ / NB, 512, 0, stream>>>(x,  W_ih0, W_hh0, b_ih0, b_hh0, h1);
    gru_mfma<H_SZ, true,  false><<<B_SZ / NB, 512, 0, stream>>>(h1, W_ih1, W_hh1, b_ih1, b_hh1, h2);
    head_kernel<<<(B_SZ * P_SZ + 255) / 256, 256, 0, stream>>>(h2, W_head, b_head, out);
}

// Round 5
// 524.252 us; speedup vs baseline: 5.7413x; 1.8320x over previous
//
#include <hip/hip_runtime.h>

// GRU_10746008175428 round 5: fused 2-layer pipelined MFMA recurrence.
// B=512 T=512 E=64 H=128 P=96.
// One 64-block kernel: blocks 0-31 = layer0 (producer), 32-63 = layer1
// (consumer), paired per 16-row batch group. Producer publishes progress
// every 8 steps (vmcnt(0) drain + barrier + agent release store); consumer
// polls with agent acquire, staying >=4 steps behind (covers distance-2
// h1 prefetch). Pair (g, g+32) -> same XCD (bid%8) for L2-local handoff.
// x pre-converted to fp16 by a parallel kernel (identical numerics to r4).
// Per-step structure (weights in VGPRs, lgkm-only barrier, pre-scaled
// gates, n-gate lo-rail) unchanged from round 4.

#define B_SZ 512
#define T_SZ 512
#define E_SZ 64
#define H_SZ 128
#define P_SZ 96
#define NB   16
#define NGRP (B_SZ / NB)          // 32
#define LO_SCALE 2048.0f
#define LO_INV   (1.0f/2048.0f)
#define SC_SIG  (-1.44269504f)   // -log2(e)
#define SC_TANH (-2.88539008f)   // -2*log2(e)

typedef _Float16 half8 __attribute__((ext_vector_type(8)));
typedef float    f32x4 __attribute__((ext_vector_type(4)));

__device__ __forceinline__ float exp2_(float x) {
#if __has_builtin(__builtin_amdgcn_exp2f)
    return __builtin_amdgcn_exp2f(x);
#else
    return exp2f(x);
#endif
}
__device__ __forceinline__ float rcp_(float x) {
#if __has_builtin(__builtin_amdgcn_rcpf)
    return __builtin_amdgcn_rcpf(x);
#else
    return 1.0f / x;
#endif
}

// XOR-swizzled byte offset in a [rows][256B] LDS tile (G4 recipe)
__device__ __forceinline__ int swz256(int row, int byte) {
    return row * 256 + (byte ^ ((row & 7) << 4));
}

// One B-fragment (16 cols x 32 k) from fp32 weight matrix W, pre-scaled.
// lane: col n0+(ln&15), k = kt*32 + (ln>>4)*8 + j.
__device__ __forceinline__ void load_bfrag(const float* __restrict__ W, int ldk,
                                           int n0, int kt, int ln, float scale,
                                           half8* hi, half8* lo) {
    int n = n0 + (ln & 15);
    int k = kt * 32 + (ln >> 4) * 8;
    const float* p = W + (size_t)n * ldk + k;
    float4 a = *(const float4*)p;
    float4 b = *(const float4*)(p + 4);
    float v[8] = {a.x, a.y, a.z, a.w, b.x, b.y, b.z, b.w};
    half8 h, l;
    #pragma unroll
    for (int j = 0; j < 8; ++j) {
        float w = v[j] * scale;
        _Float16 hh = (_Float16)w;
        h[j] = hh;
        l[j] = (_Float16)((w - (float)hh) * LO_SCALE);
    }
    *hi = h;
    if (lo) *lo = l;
}

#define LOADX(Sx, tt)                                                              \
    if ((tt) < T_SZ) {                                                             \
        _Pragma("unroll") for (int kt = 0; kt < KFX; ++kt)                         \
            Sx[kt] = *(const half8*)(xlane + (size_t)(tt) * ROWB + kt * 64);       \
    }

#define GRU_STEP(Sx, tcur, tnext)                                                  \
    {                                                                              \
        const char* hb = hs[(tcur) & 1];                                           \
        half8 ah[4];                                                               \
        _Pragma("unroll") for (int kt = 0; kt < 4; ++kt)                           \
            ah[kt] = *(const half8*)(hb + swz256(colg, kt * 64 + rgrp * 16));      \
        f32x4 ax0 = {bs0, bs0, bs0, bs0};                                          \
        f32x4 ax1 = {bs1, bs1, bs1, bs1};                                          \
        f32x4 ax2 = {bi2s, bi2s, bi2s, bi2s};                                      \
        f32x4 ah2 = {bh2s, bh2s, bh2s, bh2s};                                      \
        f32x4 ah0 = {0.f, 0.f, 0.f, 0.f};                                          \
        f32x4 ah1 = ah0, al2 = ah0;                                                \
        _Pragma("unroll") for (int kt = 0; kt < KFX; ++kt) {                       \
            ax0 = __builtin_amdgcn_mfma_f32_16x16x32_f16(Sx[kt], bx[0][kt], ax0, 0, 0, 0); \
            ax1 = __builtin_amdgcn_mfma_f32_16x16x32_f16(Sx[kt], bx[1][kt], ax1, 0, 0, 0); \
            ax2 = __builtin_amdgcn_mfma_f32_16x16x32_f16(Sx[kt], bx[2][kt], ax2, 0, 0, 0); \
        }                                                                          \
        _Pragma("unroll") for (int kt = 0; kt < 4; ++kt) {                         \
            ah0 = __builtin_amdgcn_mfma_f32_16x16x32_f16(ah[kt], bhh[0][kt], ah0, 0, 0, 0); \
            ah1 = __builtin_amdgcn_mfma_f32_16x16x32_f16(ah[kt], bhh[1][kt], ah1, 0, 0, 0); \
            ah2 = __builtin_amdgcn_mfma_f32_16x16x32_f16(ah[kt], bhh[2][kt], ah2, 0, 0, 0); \
            al2 = __builtin_amdgcn_mfma_f32_16x16x32_f16(ah[kt], bhl2[kt],   al2, 0, 0, 0); \
        }                                                                          \
        LOADX(Sx, tnext)                                                           \
        float hn_[4];                                                              \
        _Pragma("unroll") for (int j = 0; j < 4; ++j) {                            \
            float e0 = exp2_(ax0[j] + ah0[j]);                                     \
            float rr = rcp_(1.f + e0);                                             \
            float e1 = exp2_(ax1[j] + ah1[j]);                                     \
            float zz = rcp_(1.f + e1);                                             \
            float hnv = ah2[j] + al2[j] * LO_INV;                                  \
            float v  = ax2[j] + rr * hnv;                                          \
            v = fminf(fmaxf(v, -60.f), 60.f);                                      \
            float e2 = exp2_(v);                                                   \
            float nn = (1.f - e2) * rcp_(1.f + e2);                                \
            hn_[j] = nn + zz * (hreg[j] - nn);                                     \
            hreg[j] = hn_[j];                                                      \
        }                                                                          \
        char* hw = hs[((tcur) + 1) & 1];                                           \
        _Pragma("unroll") for (int j = 0; j < 4; ++j) {                            \
            int bb = rgrp * 4 + j;                                                 \
            *(_Float16*)(hw + swz256(bb, cw * 2)) = (_Float16)hn_[j];              \
            if constexpr (OUT_ALL) {                                               \
                ((_Float16*)hout)[((size_t)(b0 + bb) * T_SZ + (tcur)) * H_SZ + cw] \
                    = (_Float16)hn_[j];                                            \
            } else {                                                               \
                if ((tcur) == T_SZ - 1)                                            \
                    ((float*)hout)[(size_t)(b0 + bb) * H_SZ + cw] = hn_[j];        \
            }                                                                      \
        }                                                                          \
        /* lgkm-only barrier: keep global loads/stores in flight across steps */   \
        asm volatile("s_waitcnt lgkmcnt(0)" ::: "memory");                         \
        __builtin_amdgcn_s_barrier();                                              \
        __builtin_amdgcn_sched_barrier(0);                                         \
    }

// ROLE 0 = producer (layer 0), ROLE 1 = consumer (layer 1)
template<int K_IN, bool OUT_ALL, int ROLE>
__device__ __forceinline__ void gru_body(const _Float16* __restrict__ xin,
                                         const float* __restrict__ W_ih,
                                         const float* __restrict__ W_hh,
                                         const float* __restrict__ b_ih,
                                         const float* __restrict__ b_hh,
                                         void* __restrict__ hout,
                                         int* __restrict__ prog,
                                         int grp, char (*hs)[4096])
{
    constexpr int KFX  = K_IN / 32;
    constexpr int ROWB = K_IN * 2;     // fp16 row bytes

    const int tid  = threadIdx.x;
    const int ln   = tid & 63;
    const int wv   = tid >> 6;        // wave 0..7 -> col tile
    const int colg = ln & 15;
    const int rgrp = ln >> 4;
    const int b0   = grp * NB;
    const int cw   = wv * 16 + colg;  // hidden-unit column 0..127

    // ---- resident weight fragments (pre-scaled by gate) ----
    half8 bx[3][KFX];        // W_ih (fp16 hi only)
    half8 bhh[3][4];         // W_hh hi
    half8 bhl2[4];           // W_hh lo (x2048), n-gate only
    const float gsc[3] = {SC_SIG, SC_SIG, SC_TANH};
    #pragma unroll
    for (int g = 0; g < 3; ++g) {
        int n0 = g * 128 + wv * 16;
        #pragma unroll
        for (int kt = 0; kt < KFX; ++kt)
            load_bfrag(W_ih, K_IN, n0, kt, ln, gsc[g], &bx[g][kt], nullptr);
        #pragma unroll
        for (int kt = 0; kt < 4; ++kt)
            load_bfrag(W_hh, H_SZ, n0, kt, ln, gsc[g], &bhh[g][kt],
                       (g == 2) ? &bhl2[kt] : nullptr);
    }
    const float bs0  = SC_SIG  * (b_ih[cw] + b_hh[cw]);
    const float bs1  = SC_SIG  * (b_ih[128 + cw] + b_hh[128 + cw]);
    const float bi2s = SC_TANH * b_ih[256 + cw];
    const float bh2s = SC_TANH * b_hh[256 + cw];

    if (tid < 256) *(float4*)(hs[0] + tid * 16) = make_float4(0.f, 0.f, 0.f, 0.f);
    float hreg[4] = {0.f, 0.f, 0.f, 0.f};

    // per-lane x row base: A-row = colg (batch), k-offset rgrp*8 elems (16B)
    const char* xlane = (const char*)xin
        + (size_t)(b0 + colg) * T_SZ * ROWB
        + rgrp * 16;

    int avail = 0;
    if (ROLE == 1) {
        while (avail < 4) {
            avail = __hip_atomic_load(prog, __ATOMIC_ACQUIRE, __HIP_MEMORY_SCOPE_AGENT);
            if (avail < 4) __builtin_amdgcn_s_sleep(8);
        }
    }

    half8 Ax[KFX], Bx2[KFX];
    LOADX(Ax, 0)
    LOADX(Bx2, 1)
    __syncthreads();

    for (int t = 0; t < T_SZ; t += 2) {
        if (ROLE == 1 && avail < T_SZ) {
            const int need = (t + 4 < T_SZ) ? t + 4 : T_SZ;
            while (avail < need) {
                avail = __hip_atomic_load(prog, __ATOMIC_ACQUIRE, __HIP_MEMORY_SCOPE_AGENT);
                if (avail < need) __builtin_amdgcn_s_sleep(8);
            }
        }
        GRU_STEP(Ax,  t,     t + 2)
        GRU_STEP(Bx2, t + 1, t + 3)
        if (ROLE == 0 && (t & 7) == 6) {
            // publish progress: own stores drained -> block barrier -> release
            asm volatile("s_waitcnt vmcnt(0)" ::: "memory");
            __builtin_amdgcn_s_barrier();
            if (tid == 0)
                __hip_atomic_store(prog, t + 2, __ATOMIC_RELEASE, __HIP_MEMORY_SCOPE_AGENT);
        }
    }
}

__global__ __launch_bounds__(512)
void gru_fused(const _Float16* __restrict__ xh,  // (B,T,64) fp16
               _Float16* __restrict__ h1,        // (B,T,128) fp16
               float* __restrict__ h2,           // (B,128) f32
               const float* __restrict__ W_ih0, const float* __restrict__ W_hh0,
               const float* __restrict__ b_ih0, const float* __restrict__ b_hh0,
               const float* __restrict__ W_ih1, const float* __restrict__ W_hh1,
               const float* __restrict__ b_ih1, const float* __restrict__ b_hh1,
               int* __restrict__ prog)
{
    __shared__ __align__(16) char hs[2][4096];
    const int role = blockIdx.x >> 5;   // grid = 64
    const int grp  = blockIdx.x & 31;
    if (role == 0)
        gru_body<E_SZ, true, 0>(xh, W_ih0, W_hh0, b_ih0, b_hh0, h1, prog + grp, grp, hs);
    else
        gru_body<H_SZ, false, 1>(h1, W_ih1, W_hh1, b_ih1, b_hh1, h2, prog + grp, grp, hs);
}

__global__ __launch_bounds__(256)
void cvt_f32_f16(const float* __restrict__ in, _Float16* __restrict__ out, int n8)
{
    int i = blockIdx.x * 256 + threadIdx.x;
    if (i >= n8) return;
    const float4* p = (const float4*)in + (size_t)i * 2;
    float4 a = p[0];
    float4 b = p[1];
    half8 h;
    h[0] = (_Float16)a.x; h[1] = (_Float16)a.y; h[2] = (_Float16)a.z; h[3] = (_Float16)a.w;
    h[4] = (_Float16)b.x; h[5] = (_Float16)b.y; h[6] = (_Float16)b.z; h[7] = (_Float16)b.w;
    ((half8*)out)[i] = h;
}

__global__ __launch_bounds__(256)
void head_kernel(const float* __restrict__ h2,   // (B, H)
                 const float* __restrict__ W,    // (P, H)
                 const float* __restrict__ bias, // (P,)
                 float* __restrict__ out)        // (B, P)
{
    int idx = blockIdx.x * 256 + threadIdx.x;
    if (idx >= B_SZ * P_SZ) return;
    int b = idx / P_SZ;
    int p = idx % P_SZ;
    const float* hv = h2 + b * H_SZ;
    const float* wv = W + p * H_SZ;
    float a0 = 0.f, a1 = 0.f, a2 = 0.f, a3 = 0.f;
    #pragma unroll
    for (int i = 0; i < H_SZ; i += 4) {
        float4 h4 = *(const float4*)(hv + i);
        float4 w4 = *(const float4*)(wv + i);
        a0 += h4.x * w4.x;
        a1 += h4.y * w4.y;
        a2 += h4.z * w4.z;
        a3 += h4.w * w4.w;
    }
    out[idx] = (a0 + a1) + (a2 + a3) + bias[p];
}

extern "C" void kernel_launch(void* const* d_in, const int* in_sizes, int n_in,
                              void* d_out, int out_size, void* d_ws, size_t ws_size,
                              hipStream_t stream)
{
    const float* x      = (const float*)d_in[0];
    const float* W_ih0  = (const float*)d_in[1];
    const float* W_hh0  = (const float*)d_in[2];
    const float* b_ih0  = (const float*)d_in[3];
    const float* b_hh0  = (const float*)d_in[4];
    const float* W_ih1  = (const float*)d_in[5];
    const float* W_hh1  = (const float*)d_in[6];
    const float* b_ih1  = (const float*)d_in[7];
    const float* b_hh1  = (const float*)d_in[8];
    const float* W_head = (const float*)d_in[9];
    const float* b_head = (const float*)d_in[10];
    float* out = (float*)d_out;

    char* ws = (char*)d_ws;
    _Float16* h1  = (_Float16*)ws;                              // 64 MiB (B,T,128) fp16
    _Float16* xh  = (_Float16*)(ws + (64u << 20));              // 32 MiB (B,T,64)  fp16
    float*    h2  = (float*)   (ws + (96u << 20));              // 256 KiB (B,128)  f32
    int*      prg = (int*)     (ws + (96u << 20) + (256u << 10));

    hipMemsetAsync(prg, 0, NGRP * sizeof(int), stream);
    cvt_f32_f16<<<(B_SZ * T_SZ * E_SZ / 8 + 255) / 256, 256, 0, stream>>>(x, xh, B_SZ * T_SZ * E_SZ / 8);
    gru_fused<<<2 * NGRP, 512, 0, stream>>>(xh, h1, h2,
                                            W_ih0, W_hh0, b_ih0, b_hh0,
                                            W_ih1, W_hh1, b_ih1, b_hh1, prg);
    head_kernel<<<(B_SZ * P_SZ + 255) / 256, 256, 0, stream>>>(h2, W_head, b_head, out);
}